// Round 1
// baseline (10959.376 us; speedup 1.0000x reference)
//
#include <hip/hip_runtime.h>

// GraphSAGE mean-aggregator layer:
//   out = D^{-1} A (x W + b)   ==   (D^{-1} A x) W + b·[deg>0]
// (linear commutes with mean), so: scatter-aggregate x, then GEMM with
// fused inv-deg scale + masked bias.

#define N_NODES 100000
#define FEATS   256

// ---------------------------------------------------------------------------
// Scatter: agg[row] += x[col]; deg[row] += 1.  One wave (64 lanes) per edge:
// lane l handles feats 4l..4l+3 via float4 gather + 4 scalar f32 atomics.
// ---------------------------------------------------------------------------
__global__ __launch_bounds__(256) void sage_scatter_kernel(
    const float* __restrict__ x, const int* __restrict__ edges,
    float* __restrict__ agg, unsigned* __restrict__ deg, int n_edges)
{
    const int wave = threadIdx.x >> 6;
    const int lane = threadIdx.x & 63;
    const int e = blockIdx.x * 4 + wave;
    if (e >= n_edges) return;

    const int row = edges[e];            // destination (segment id)
    const int col = edges[n_edges + e];  // source (gathered)

    const float4 v = *(const float4*)(x + (size_t)col * FEATS + lane * 4);
    float* dst = agg + (size_t)row * FEATS + lane * 4;
    atomicAdd(dst + 0, v.x);
    atomicAdd(dst + 1, v.y);
    atomicAdd(dst + 2, v.z);
    atomicAdd(dst + 3, v.w);
    if (lane == 0) atomicAdd(deg + row, 1u);
}

// ---------------------------------------------------------------------------
// GEMM: out[n][c] = inv_deg[n] * sum_k agg[n][k] * W[k][c] + b[c]*[deg>0]
// fp32 (no fp32 MFMA on CDNA4). 64x64 tile, 256 threads, 4x4 reg tile.
// LDS pad to 68 floats/row: keeps float4 (ds_read_b128) 16B-aligned and
// read conflicts <=2-way (free).
// ---------------------------------------------------------------------------
__global__ __launch_bounds__(256) void sage_gemm_kernel(
    const float* __restrict__ agg, const float* __restrict__ W,
    const float* __restrict__ bias, const unsigned* __restrict__ deg,
    float* __restrict__ out)
{
    __shared__ float aT[64][68];   // [k][row] (transposed A chunk)
    __shared__ float wS[64][68];   // [k][col]

    const int tid = threadIdx.x;
    const int tx = tid & 15;       // col group
    const int ty = tid >> 4;       // row group
    const int row0 = blockIdx.x * 64;
    const int col0 = blockIdx.y * 64;

    float acc[4][4] = {};

    for (int k0 = 0; k0 < FEATS; k0 += 64) {
        __syncthreads();
        // Stage A (transposed) and W chunk: 2x 1024 float4, 256 threads.
        #pragma unroll
        for (int i = 0; i < 4; ++i) {
            const int lin = i * 256 + tid;       // 0..1023
            const int r  = lin >> 4;             // 0..63
            const int kk = (lin & 15) << 2;      // 0..60

            const int grow = row0 + r;
            float4 av = make_float4(0.f, 0.f, 0.f, 0.f);
            if (grow < N_NODES)
                av = *(const float4*)(agg + (size_t)grow * FEATS + k0 + kk);
            aT[kk + 0][r] = av.x;
            aT[kk + 1][r] = av.y;
            aT[kk + 2][r] = av.z;
            aT[kk + 3][r] = av.w;

            const float4 wv =
                *(const float4*)(W + (size_t)(k0 + r) * FEATS + col0 + kk);
            *(float4*)&wS[r][kk] = wv;
        }
        __syncthreads();

        #pragma unroll
        for (int k = 0; k < 64; ++k) {
            const float4 a = *(const float4*)&aT[k][ty << 2];
            const float4 w = *(const float4*)&wS[k][tx << 2];
            const float av[4] = {a.x, a.y, a.z, a.w};
            const float wv[4] = {w.x, w.y, w.z, w.w};
            #pragma unroll
            for (int i = 0; i < 4; ++i)
                #pragma unroll
                for (int j = 0; j < 4; ++j)
                    acc[i][j] = fmaf(av[i], wv[j], acc[i][j]);
        }
    }

    // Epilogue: scale by inv_deg, add masked bias, float4 store.
    #pragma unroll
    for (int i = 0; i < 4; ++i) {
        const int grow = row0 + (ty << 2) + i;
        if (grow >= N_NODES) continue;
        const unsigned d = deg[grow];
        const float s  = d ? 1.0f / (float)d : 0.0f;
        const float bm = d ? 1.0f : 0.0f;
        const int gcol = col0 + (tx << 2);
        float4 o;
        o.x = acc[i][0] * s + bm * bias[gcol + 0];
        o.y = acc[i][1] * s + bm * bias[gcol + 1];
        o.z = acc[i][2] * s + bm * bias[gcol + 2];
        o.w = acc[i][3] * s + bm * bias[gcol + 3];
        *(float4*)(out + (size_t)grow * FEATS + gcol) = o;
    }
}

// ---------------------------------------------------------------------------
extern "C" void kernel_launch(void* const* d_in, const int* in_sizes, int n_in,
                              void* d_out, int out_size, void* d_ws, size_t ws_size,
                              hipStream_t stream)
{
    const float* x     = (const float*)d_in[0];
    const int*   edges = (const int*)d_in[1];   // [2][n_edges], int32
    const float* W     = (const float*)d_in[2];
    const float* bias  = (const float*)d_in[3];
    float* out = (float*)d_out;

    const int n_edges = in_sizes[1] / 2;

    const size_t agg_bytes = (size_t)N_NODES * FEATS * sizeof(float);
    float*    agg = (float*)d_ws;
    unsigned* deg = (unsigned*)((char*)d_ws + agg_bytes);

    hipMemsetAsync(d_ws, 0, agg_bytes + (size_t)N_NODES * sizeof(unsigned), stream);

    const int blocks = (n_edges + 3) / 4;
    sage_scatter_kernel<<<blocks, 256, 0, stream>>>(x, edges, agg, deg, n_edges);

    dim3 grid((N_NODES + 63) / 64, FEATS / 64);
    sage_gemm_kernel<<<grid, 256, 0, stream>>>(agg, W, bias, deg, out);
}

// Round 2
// 973.511 us; speedup vs baseline: 11.2576x; 11.2576x over previous
//
#include <hip/hip_runtime.h>

// GraphSAGE mean-aggregator layer:
//   out = D^{-1} A (x W + b)  ==  (D^{-1} A x) W + b·[deg>0]
// Pipeline: deg-count -> exclusive scan (rowptr) -> CSR fill -> atomic-free
// gather (one wave per node) -> fp32 GEMM with fused inv-deg + masked bias.

#define N_NODES 100000
#define FEATS   256
#define SCAN_BLK 512

// ---------------------------------------------------------------------------
// 1) Degree count: 3.2M int atomics (vs 819M float atomics before).
// ---------------------------------------------------------------------------
__global__ __launch_bounds__(256) void deg_count_kernel(
    const int* __restrict__ edges, unsigned* __restrict__ deg, int n_edges)
{
    const int e = blockIdx.x * 256 + threadIdx.x;
    if (e >= n_edges) return;
    atomicAdd(deg + edges[e], 1u);
}

// ---------------------------------------------------------------------------
// 2) Exclusive scan of deg -> rowptr.  Three tiny kernels.
// ---------------------------------------------------------------------------
__global__ __launch_bounds__(SCAN_BLK) void scan_partials_kernel(
    const unsigned* __restrict__ deg, unsigned* __restrict__ part, int n)
{
    __shared__ unsigned s[SCAN_BLK / 64];
    const int i = blockIdx.x * SCAN_BLK + threadIdx.x;
    unsigned v = (i < n) ? deg[i] : 0u;
    #pragma unroll
    for (int off = 32; off >= 1; off >>= 1) v += __shfl_down(v, off);
    if ((threadIdx.x & 63) == 0) s[threadIdx.x >> 6] = v;
    __syncthreads();
    if (threadIdx.x == 0) {
        unsigned t = 0;
        #pragma unroll
        for (int w = 0; w < SCAN_BLK / 64; ++w) t += s[w];
        part[blockIdx.x] = t;
    }
}

__global__ void scan_spine_kernel(unsigned* part, int nb)
{
    if (threadIdx.x == 0 && blockIdx.x == 0) {
        unsigned run = 0;
        for (int i = 0; i < nb; ++i) { unsigned t = part[i]; part[i] = run; run += t; }
    }
}

__global__ __launch_bounds__(SCAN_BLK) void scan_final_kernel(
    const unsigned* __restrict__ deg, const unsigned* __restrict__ part,
    unsigned* __restrict__ rowptr, int n)
{
    __shared__ unsigned s[SCAN_BLK];
    const int i = blockIdx.x * SCAN_BLK + threadIdx.x;
    const unsigned v = (i < n) ? deg[i] : 0u;
    s[threadIdx.x] = v;
    __syncthreads();
    // Hillis-Steele inclusive scan
    for (int off = 1; off < SCAN_BLK; off <<= 1) {
        unsigned t = (threadIdx.x >= (unsigned)off) ? s[threadIdx.x - off] : 0u;
        __syncthreads();
        s[threadIdx.x] += t;
        __syncthreads();
    }
    if (i < n) rowptr[i] = part[blockIdx.x] + s[threadIdx.x] - v;  // exclusive
}

// ---------------------------------------------------------------------------
// 3) CSR fill: bucket col indices by row.  3.2M int atomics on cursors.
// ---------------------------------------------------------------------------
__global__ __launch_bounds__(256) void csr_fill_kernel(
    const int* __restrict__ edges, const unsigned* __restrict__ rowptr,
    unsigned* __restrict__ cursor, int* __restrict__ csr_col, int n_edges)
{
    const int e = blockIdx.x * 256 + threadIdx.x;
    if (e >= n_edges) return;
    const int row = edges[e];
    const int col = edges[n_edges + e];
    const unsigned pos = rowptr[row] + atomicAdd(cursor + row, 1u);
    csr_col[pos] = col;
}

// ---------------------------------------------------------------------------
// 4) Gather: agg[n] = sum_{c in N(n)} x[c].  One wave per node, lane owns
//    feats 4l..4l+3 (float4).  No atomics; x (102 MB) is L3-resident.
// ---------------------------------------------------------------------------
__global__ __launch_bounds__(256) void gather_kernel(
    const float* __restrict__ x, const int* __restrict__ csr_col,
    const unsigned* __restrict__ rowptr, const unsigned* __restrict__ deg,
    float* __restrict__ agg)
{
    const int node = blockIdx.x * 4 + (threadIdx.x >> 6);
    const int lane = threadIdx.x & 63;
    if (node >= N_NODES) return;

    const unsigned start = rowptr[node];
    const unsigned cnt   = deg[node];

    float4 acc = make_float4(0.f, 0.f, 0.f, 0.f);
    unsigned j = 0;
    for (; j + 4 <= cnt; j += 4) {                 // 4-way unroll for MLP/ILP
        const int c0 = csr_col[start + j + 0];
        const int c1 = csr_col[start + j + 1];
        const int c2 = csr_col[start + j + 2];
        const int c3 = csr_col[start + j + 3];
        const float4 v0 = *(const float4*)(x + (size_t)c0 * FEATS + lane * 4);
        const float4 v1 = *(const float4*)(x + (size_t)c1 * FEATS + lane * 4);
        const float4 v2 = *(const float4*)(x + (size_t)c2 * FEATS + lane * 4);
        const float4 v3 = *(const float4*)(x + (size_t)c3 * FEATS + lane * 4);
        acc.x += v0.x + v1.x + v2.x + v3.x;
        acc.y += v0.y + v1.y + v2.y + v3.y;
        acc.z += v0.z + v1.z + v2.z + v3.z;
        acc.w += v0.w + v1.w + v2.w + v3.w;
    }
    for (; j < cnt; ++j) {
        const int c = csr_col[start + j];
        const float4 v = *(const float4*)(x + (size_t)c * FEATS + lane * 4);
        acc.x += v.x; acc.y += v.y; acc.z += v.z; acc.w += v.w;
    }
    *(float4*)(agg + (size_t)node * FEATS + lane * 4) = acc;
}

// ---------------------------------------------------------------------------
// 5) GEMM: out = inv_deg * (agg @ W) + b*[deg>0].  fp32, 64x64 tile,
//    256 threads, 4x4 reg tile, LDS pad 68 (16B-aligned, <=2-way conflicts).
// ---------------------------------------------------------------------------
__global__ __launch_bounds__(256) void sage_gemm_kernel(
    const float* __restrict__ agg, const float* __restrict__ W,
    const float* __restrict__ bias, const unsigned* __restrict__ deg,
    float* __restrict__ out)
{
    __shared__ float aT[64][68];   // [k][row]
    __shared__ float wS[64][68];   // [k][col]

    const int tid = threadIdx.x;
    const int tx = tid & 15;
    const int ty = tid >> 4;
    const int row0 = blockIdx.x * 64;
    const int col0 = blockIdx.y * 64;

    float acc[4][4] = {};

    for (int k0 = 0; k0 < FEATS; k0 += 64) {
        __syncthreads();
        #pragma unroll
        for (int i = 0; i < 4; ++i) {
            const int lin = i * 256 + tid;
            const int r  = lin >> 4;
            const int kk = (lin & 15) << 2;

            const int grow = row0 + r;
            float4 av = make_float4(0.f, 0.f, 0.f, 0.f);
            if (grow < N_NODES)
                av = *(const float4*)(agg + (size_t)grow * FEATS + k0 + kk);
            aT[kk + 0][r] = av.x;
            aT[kk + 1][r] = av.y;
            aT[kk + 2][r] = av.z;
            aT[kk + 3][r] = av.w;

            *(float4*)&wS[r][kk] =
                *(const float4*)(W + (size_t)(k0 + r) * FEATS + col0 + kk);
        }
        __syncthreads();

        #pragma unroll
        for (int k = 0; k < 64; ++k) {
            const float4 a = *(const float4*)&aT[k][ty << 2];
            const float4 w = *(const float4*)&wS[k][tx << 2];
            const float av[4] = {a.x, a.y, a.z, a.w};
            const float wv[4] = {w.x, w.y, w.z, w.w};
            #pragma unroll
            for (int i = 0; i < 4; ++i)
                #pragma unroll
                for (int j = 0; j < 4; ++j)
                    acc[i][j] = fmaf(av[i], wv[j], acc[i][j]);
        }
    }

    #pragma unroll
    for (int i = 0; i < 4; ++i) {
        const int grow = row0 + (ty << 2) + i;
        if (grow >= N_NODES) continue;
        const unsigned d = deg[grow];
        const float s  = d ? 1.0f / (float)d : 0.0f;
        const float bm = d ? 1.0f : 0.0f;
        const int gcol = col0 + (tx << 2);
        float4 o;
        o.x = acc[i][0] * s + bm * bias[gcol + 0];
        o.y = acc[i][1] * s + bm * bias[gcol + 1];
        o.z = acc[i][2] * s + bm * bias[gcol + 2];
        o.w = acc[i][3] * s + bm * bias[gcol + 3];
        *(float4*)(out + (size_t)grow * FEATS + gcol) = o;
    }
}

// ---------------------------------------------------------------------------
extern "C" void kernel_launch(void* const* d_in, const int* in_sizes, int n_in,
                              void* d_out, int out_size, void* d_ws, size_t ws_size,
                              hipStream_t stream)
{
    const float* x     = (const float*)d_in[0];
    const int*   edges = (const int*)d_in[1];   // [2][n_edges] int32
    const float* W     = (const float*)d_in[2];
    const float* bias  = (const float*)d_in[3];
    float* out = (float*)d_out;

    const int n_edges = in_sizes[1] / 2;

    // Workspace layout (all 256B-aligned):
    char* p = (char*)d_ws;
    float*    agg    = (float*)p;            p += (size_t)N_NODES * FEATS * sizeof(float);
    unsigned* deg    = (unsigned*)p;         p += ((size_t)N_NODES * 4 + 255) / 256 * 256;
    unsigned* cursor = (unsigned*)p;         p += ((size_t)N_NODES * 4 + 255) / 256 * 256;
    unsigned* rowptr = (unsigned*)p;         p += ((size_t)N_NODES * 4 + 255) / 256 * 256;
    unsigned* part   = (unsigned*)p;         p += 4096;
    int*      csr    = (int*)p;              /* n_edges * 4 bytes */

    // Zero deg + cursor (adjacent): 2 aligned regions
    hipMemsetAsync(deg, 0, ((size_t)N_NODES * 4 + 255) / 256 * 256 * 2, stream);

    const int eb = (n_edges + 255) / 256;
    deg_count_kernel<<<eb, 256, 0, stream>>>(edges, deg, n_edges);

    const int nb = (N_NODES + SCAN_BLK - 1) / SCAN_BLK;   // 196
    scan_partials_kernel<<<nb, SCAN_BLK, 0, stream>>>(deg, part, N_NODES);
    scan_spine_kernel<<<1, 64, 0, stream>>>(part, nb);
    scan_final_kernel<<<nb, SCAN_BLK, 0, stream>>>(deg, part, rowptr, N_NODES);

    csr_fill_kernel<<<eb, 256, 0, stream>>>(edges, rowptr, cursor, csr, n_edges);

    gather_kernel<<<(N_NODES + 3) / 4, 256, 0, stream>>>(x, csr, rowptr, deg, agg);

    dim3 grid((N_NODES + 63) / 64, FEATS / 64);
    sage_gemm_kernel<<<grid, 256, 0, stream>>>(agg, W, bias, deg, out);
}

// Round 3
// 697.284 us; speedup vs baseline: 15.7172x; 1.3961x over previous
//
#include <hip/hip_runtime.h>

// GraphSAGE mean-aggregator:
//   out = D^{-1} A (x W + b)  ==  (D^{-1} A x) W + b·[deg>0]
// Pipeline: x->bf16, W->bf16 transposed, deg-count, scan, CSR fill,
// atomic-free bf16 gather (one wave/node), bf16 MFMA GEMM with fused
// inv-deg + masked bias epilogue.

#define N_NODES 100000
#define FEATS   256
#define SCAN_BLK 512

typedef __attribute__((ext_vector_type(4))) short s16x4;
typedef __attribute__((ext_vector_type(8))) short s16x8;
typedef __attribute__((ext_vector_type(4))) float f32x4;

__device__ __forceinline__ float bf2f(short h) {
    unsigned u = ((unsigned)(unsigned short)h) << 16;
    return __builtin_bit_cast(float, u);
}
__device__ __forceinline__ short f2bf(float f) {   // round-to-nearest-even
    unsigned u = __builtin_bit_cast(unsigned, f);
    u = (u + 0x7FFFu + ((u >> 16) & 1u)) >> 16;
    return (short)u;
}

// ---------------------------------------------------------------------------
// x (fp32) -> xb (bf16).  One float4 per thread; 25000 blocks exactly.
// ---------------------------------------------------------------------------
__global__ __launch_bounds__(256) void convert_x_kernel(
    const float* __restrict__ x, short* __restrict__ xb)
{
    const size_t i = (size_t)blockIdx.x * 256 + threadIdx.x;
    const float4 v = *(const float4*)(x + i * 4);
    s16x4 o;
    o.x = f2bf(v.x); o.y = f2bf(v.y); o.z = f2bf(v.z); o.w = f2bf(v.w);
    *(s16x4*)(xb + i * 4) = o;
}

// W[k][n] fp32 -> Wt[n][k] bf16 (transposed so GEMM B-staging is coalesced).
__global__ void convert_w_kernel(const float* __restrict__ W,
                                 short* __restrict__ Wt)
{
    const int k = blockIdx.x, n = threadIdx.x;
    Wt[n * FEATS + k] = f2bf(W[k * FEATS + n]);
}

// ---------------------------------------------------------------------------
// Degree count (3.2M int atomics).
// ---------------------------------------------------------------------------
__global__ __launch_bounds__(256) void deg_count_kernel(
    const int* __restrict__ edges, unsigned* __restrict__ deg, int n_edges)
{
    const int e = blockIdx.x * 256 + threadIdx.x;
    if (e >= n_edges) return;
    atomicAdd(deg + edges[e], 1u);
}

// ---------------------------------------------------------------------------
// Exclusive scan deg -> rowptr (3 tiny kernels).
// ---------------------------------------------------------------------------
__global__ __launch_bounds__(SCAN_BLK) void scan_partials_kernel(
    const unsigned* __restrict__ deg, unsigned* __restrict__ part, int n)
{
    __shared__ unsigned s[SCAN_BLK / 64];
    const int i = blockIdx.x * SCAN_BLK + threadIdx.x;
    unsigned v = (i < n) ? deg[i] : 0u;
    #pragma unroll
    for (int off = 32; off >= 1; off >>= 1) v += __shfl_down(v, off);
    if ((threadIdx.x & 63) == 0) s[threadIdx.x >> 6] = v;
    __syncthreads();
    if (threadIdx.x == 0) {
        unsigned t = 0;
        #pragma unroll
        for (int w = 0; w < SCAN_BLK / 64; ++w) t += s[w];
        part[blockIdx.x] = t;
    }
}

__global__ void scan_spine_kernel(unsigned* part, int nb)
{
    if (threadIdx.x == 0 && blockIdx.x == 0) {
        unsigned run = 0;
        for (int i = 0; i < nb; ++i) { unsigned t = part[i]; part[i] = run; run += t; }
    }
}

__global__ __launch_bounds__(SCAN_BLK) void scan_final_kernel(
    const unsigned* __restrict__ deg, const unsigned* __restrict__ part,
    unsigned* __restrict__ rowptr, int n)
{
    __shared__ unsigned s[SCAN_BLK];
    const int i = blockIdx.x * SCAN_BLK + threadIdx.x;
    const unsigned v = (i < n) ? deg[i] : 0u;
    s[threadIdx.x] = v;
    __syncthreads();
    for (int off = 1; off < SCAN_BLK; off <<= 1) {
        unsigned t = (threadIdx.x >= (unsigned)off) ? s[threadIdx.x - off] : 0u;
        __syncthreads();
        s[threadIdx.x] += t;
        __syncthreads();
    }
    if (i < n) rowptr[i] = part[blockIdx.x] + s[threadIdx.x] - v;  // exclusive
}

// ---------------------------------------------------------------------------
// CSR fill: bump rowptr in place (it becomes the END pointer; gather
// recovers start = rowptr[row] - deg[row]).  Saves the cursor array.
// ---------------------------------------------------------------------------
__global__ __launch_bounds__(256) void csr_fill_kernel(
    const int* __restrict__ edges, unsigned* __restrict__ rowptr,
    int* __restrict__ csr_col, int n_edges)
{
    const int e = blockIdx.x * 256 + threadIdx.x;
    if (e >= n_edges) return;
    const int row = edges[e];
    const int col = edges[n_edges + e];
    const unsigned pos = atomicAdd(rowptr + row, 1u);
    csr_col[pos] = col;
}

// ---------------------------------------------------------------------------
// Gather (bf16): aggb[n] = bf16( sum_{c in N(n)} xb[c] ).  One wave/node,
// lane owns 4 feats (8 B loads), fp32 accumulate.  No atomics.
// ---------------------------------------------------------------------------
__global__ __launch_bounds__(256) void gather_kernel(
    const short* __restrict__ xb, const int* __restrict__ csr_col,
    const unsigned* __restrict__ rowptr_end, const unsigned* __restrict__ deg,
    short* __restrict__ aggb)
{
    const int node = blockIdx.x * 4 + (threadIdx.x >> 6);
    const int lane = threadIdx.x & 63;
    if (node >= N_NODES) return;

    const unsigned cnt   = deg[node];
    const unsigned start = rowptr_end[node] - cnt;

    float a0 = 0.f, a1 = 0.f, a2 = 0.f, a3 = 0.f;
    unsigned j = 0;
    for (; j + 4 <= cnt; j += 4) {
        const int c0 = csr_col[start + j + 0];
        const int c1 = csr_col[start + j + 1];
        const int c2 = csr_col[start + j + 2];
        const int c3 = csr_col[start + j + 3];
        const s16x4 v0 = *(const s16x4*)(xb + (size_t)c0 * FEATS + lane * 4);
        const s16x4 v1 = *(const s16x4*)(xb + (size_t)c1 * FEATS + lane * 4);
        const s16x4 v2 = *(const s16x4*)(xb + (size_t)c2 * FEATS + lane * 4);
        const s16x4 v3 = *(const s16x4*)(xb + (size_t)c3 * FEATS + lane * 4);
        a0 += bf2f(v0.x) + bf2f(v1.x) + bf2f(v2.x) + bf2f(v3.x);
        a1 += bf2f(v0.y) + bf2f(v1.y) + bf2f(v2.y) + bf2f(v3.y);
        a2 += bf2f(v0.z) + bf2f(v1.z) + bf2f(v2.z) + bf2f(v3.z);
        a3 += bf2f(v0.w) + bf2f(v1.w) + bf2f(v2.w) + bf2f(v3.w);
    }
    for (; j < cnt; ++j) {
        const int c = csr_col[start + j];
        const s16x4 v = *(const s16x4*)(xb + (size_t)c * FEATS + lane * 4);
        a0 += bf2f(v.x); a1 += bf2f(v.y); a2 += bf2f(v.z); a3 += bf2f(v.w);
    }
    s16x4 o;
    o.x = f2bf(a0); o.y = f2bf(a1); o.z = f2bf(a2); o.w = f2bf(a3);
    *(s16x4*)(aggb + (size_t)node * FEATS + lane * 4) = o;
}

// ---------------------------------------------------------------------------
// MFMA GEMM: out = inv_deg * (aggb @ W) + b*[deg>0].
// 128x128 tile, 256 thr = 2x2 waves of 64x64, 16x16x32 bf16 MFMA.
// LDS pad 72 shorts/row: 16B-aligned, ds_read conflicts <=2-way (free).
// A and B frags both read 8 contiguous k at the same offset -> internal
// k-permutation cancels; D layout per verified mapping (m89).
// ---------------------------------------------------------------------------
__global__ __launch_bounds__(256) void sage_gemm_kernel(
    const short* __restrict__ aggb, const short* __restrict__ Wt,
    const float* __restrict__ bias, const unsigned* __restrict__ deg,
    float* __restrict__ out)
{
    __shared__ short aS[128][72];   // [row][k]
    __shared__ short bS[128][72];   // [col][k]  (Wt is [n][k])

    const int tid  = threadIdx.x;
    const int lane = tid & 63;
    const int wave = tid >> 6;
    const int wr = wave >> 1, wc = wave & 1;   // 2x2 waves, 64x64 each
    const int fr = lane & 15, fq = lane >> 4;
    const int row0 = blockIdx.x * 128;
    const int col0 = blockIdx.y * 128;

    f32x4 acc[4][4] = {};

    for (int k0 = 0; k0 < FEATS; k0 += 64) {
        if (k0) __syncthreads();
        #pragma unroll
        for (int i = 0; i < 4; ++i) {
            const int lin = i * 256 + tid;     // 0..1023
            const int r  = lin >> 3;           // 0..127
            const int kk = (lin & 7) << 3;     // 0..56
            const int grow = row0 + r;
            s16x8 av = {};
            if (grow < N_NODES)
                av = *(const s16x8*)(aggb + (size_t)grow * FEATS + k0 + kk);
            *(s16x8*)&aS[r][kk] = av;
            *(s16x8*)&bS[r][kk] =
                *(const s16x8*)(Wt + (size_t)(col0 + r) * FEATS + k0 + kk);
        }
        __syncthreads();

        #pragma unroll
        for (int ko = 0; ko < 64; ko += 32) {
            s16x8 af[4], bg[4];
            #pragma unroll
            for (int m = 0; m < 4; ++m)
                af[m] = *(const s16x8*)&aS[wr * 64 + m * 16 + fr][ko + fq * 8];
            #pragma unroll
            for (int n = 0; n < 4; ++n)
                bg[n] = *(const s16x8*)&bS[wc * 64 + n * 16 + fr][ko + fq * 8];
            #pragma unroll
            for (int m = 0; m < 4; ++m)
                #pragma unroll
                for (int n = 0; n < 4; ++n)
                    acc[m][n] = __builtin_amdgcn_mfma_f32_16x16x32_bf16(
                        af[m], bg[n], acc[m][n], 0, 0, 0);
        }
    }

    #pragma unroll
    for (int m = 0; m < 4; ++m) {
        #pragma unroll
        for (int j = 0; j < 4; ++j) {
            const int row = row0 + wr * 64 + m * 16 + fq * 4 + j;
            if (row >= N_NODES) continue;
            const unsigned d = deg[row];
            const float s  = d ? 1.0f / (float)d : 0.0f;
            const float bm = d ? 1.0f : 0.0f;
            #pragma unroll
            for (int n = 0; n < 4; ++n) {
                const int col = col0 + wc * 64 + n * 16 + fr;
                out[(size_t)row * FEATS + col] = acc[m][n][j] * s + bm * bias[col];
            }
        }
    }
}

// ---------------------------------------------------------------------------
extern "C" void kernel_launch(void* const* d_in, const int* in_sizes, int n_in,
                              void* d_out, int out_size, void* d_ws, size_t ws_size,
                              hipStream_t stream)
{
    const float* x     = (const float*)d_in[0];
    const int*   edges = (const int*)d_in[1];   // [2][n_edges] int32
    const float* W     = (const float*)d_in[2];
    const float* bias  = (const float*)d_in[3];
    float* out = (float*)d_out;

    const int n_edges = in_sizes[1] / 2;

    // Workspace layout (256B-aligned chunks):
    char* p = (char*)d_ws;
    short*    xb     = (short*)p;     p += (size_t)N_NODES * FEATS * 2;         // 51.2 MB
    short*    aggb   = (short*)p;     p += (size_t)N_NODES * FEATS * 2;         // 51.2 MB
    short*    Wt     = (short*)p;     p += (size_t)FEATS * FEATS * 2;           // 128 KB
    unsigned* deg    = (unsigned*)p;  p += ((size_t)N_NODES * 4 + 255) / 256 * 256;
    unsigned* rowptr = (unsigned*)p;  p += ((size_t)N_NODES * 4 + 255) / 256 * 256;
    unsigned* part   = (unsigned*)p;  p += 4096;
    int*      csr    = (int*)p;       /* n_edges * 4 B */

    hipMemsetAsync(deg, 0, (size_t)N_NODES * sizeof(unsigned), stream);

    convert_x_kernel<<<(N_NODES * FEATS) / (256 * 4), 256, 0, stream>>>(x, xb);
    convert_w_kernel<<<FEATS, FEATS, 0, stream>>>(W, Wt);

    const int eb = (n_edges + 255) / 256;
    deg_count_kernel<<<eb, 256, 0, stream>>>(edges, deg, n_edges);

    const int nb = (N_NODES + SCAN_BLK - 1) / SCAN_BLK;
    scan_partials_kernel<<<nb, SCAN_BLK, 0, stream>>>(deg, part, N_NODES);
    scan_spine_kernel<<<1, 64, 0, stream>>>(part, nb);
    scan_final_kernel<<<nb, SCAN_BLK, 0, stream>>>(deg, part, rowptr, N_NODES);

    csr_fill_kernel<<<eb, 256, 0, stream>>>(edges, rowptr, csr, n_edges);

    gather_kernel<<<(N_NODES + 3) / 4, 256, 0, stream>>>(xb, csr, rowptr, deg, aggb);

    dim3 grid((N_NODES + 127) / 128, FEATS / 128);
    sage_gemm_kernel<<<grid, 256, 0, stream>>>(aggb, Wt, bias, deg, out);
}